// Round 3
// baseline (87.473 us; speedup 1.0000x reference)
//
#include <hip/hip_runtime.h>

typedef unsigned int   u32;
typedef unsigned short u16;
typedef __bf16 bf16x8 __attribute__((ext_vector_type(8)));
typedef float  f32x4  __attribute__((ext_vector_type(4)));

__device__ __forceinline__ u16 f2b(float f) {
  u32 u = __float_as_uint(f);
  u = (u + 0x7fffu + ((u >> 16) & 1u)) >> 16;   // RNE
  return (u16)u;
}
__device__ __forceinline__ float b2f_lo(u32 u) { return __uint_as_float(u << 16); }
__device__ __forceinline__ float b2f_hi(u32 u) { return __uint_as_float(u & 0xffff0000u); }
__device__ __forceinline__ float silu_f(float x) { return __fdividef(x, 1.f + __expf(-x)); }

// ---------- prep: Wk/Wq (256x256 f32, [k][n]) -> bf16 [n][k] ----------
__global__ void prep_wt(const float* __restrict__ Wk, const float* __restrict__ Wq,
                        u16* __restrict__ Wkt, u16* __restrict__ Wqt) {
  for (int idx = blockIdx.x * 256 + threadIdx.x; idx < 256 * 256; idx += gridDim.x * 256) {
    int n = idx >> 8, k = idx & 255;
    Wkt[idx] = f2b(Wk[k * 256 + n]);
    Wqt[idx] = f2b(Wq[k * 256 + n]);
  }
}

// ---------- prep: W0[h][l][j] -> W0t[h][j][l], W1[h][j][k] -> W1t[h][k][j] (f32) ----------
__global__ void prep_mlpw(const float* __restrict__ W0, const float* __restrict__ W1,
                          float* __restrict__ W0t, float* __restrict__ W1t) {
  int t = threadIdx.x;
  for (int i = t; i < 8 * 16 * 10; i += 256) {
    int h = i / 160, r = i % 160, j = r / 10, l = r % 10;
    W0t[i] = W0[h * 160 + l * 16 + j];
  }
  for (int i = t; i < 8 * 16 * 16; i += 256) {
    int h = i >> 8, r = i & 255, k = r >> 4, j = r & 15;
    W1t[i] = W1[h * 256 + j * 16 + k];
  }
}

// ---------- GEMM: C_bf16[8192][256] = A_f32[8192][256] @ W + bias ----------
// B supplied transposed+bf16: Bt[n][k]. Tile 128x128, BK=64, 4 waves (2x2 of 64x64).
#define LDA 72
__global__ __launch_bounds__(256) void gemm_proj(
    const float* __restrict__ A0, const float* __restrict__ A1,
    const u16* __restrict__ B0, const u16* __restrict__ B1,
    const float* __restrict__ bias0, const float* __restrict__ bias1,
    u16* __restrict__ C0, u16* __restrict__ C1) {
  const float* A; const u16* Bt; const float* bias; u16* C;
  if (blockIdx.z == 0) { A = A0; Bt = B0; bias = bias0; C = C0; }
  else                 { A = A1; Bt = B1; bias = bias1; C = C1; }
  __shared__ __align__(16) u16 As[128 * LDA];
  __shared__ __align__(16) u16 Bs[128 * LDA];
  const int t = threadIdx.x;
  const int w = t >> 6, lane = t & 63;
  const int wm = w >> 1, wn = w & 1;
  const int row0 = blockIdx.x * 128, col0 = blockIdx.y * 128;
  f32x4 acc[4][4] = {};
  for (int kk = 0; kk < 256; kk += 64) {
    // stage A (f32 -> bf16), 128 rows x 64 k
    #pragma unroll
    for (int p = 0; p < 8; p++) {
      int r = p * 16 + (t >> 4), q = (t & 15) * 4;
      float4 v = *(const float4*)(A + (size_t)(row0 + r) * 256 + kk + q);
      uint2 pk;
      pk.x = (u32)f2b(v.x) | ((u32)f2b(v.y) << 16);
      pk.y = (u32)f2b(v.z) | ((u32)f2b(v.w) << 16);
      *(uint2*)(&As[r * LDA + q]) = pk;
    }
    // stage B (already bf16), 128 cols x 64 k
    #pragma unroll
    for (int p = 0; p < 4; p++) {
      int r = p * 32 + (t >> 3), q = (t & 7) * 8;
      *(uint4*)(&Bs[r * LDA + q]) = *(const uint4*)(Bt + (size_t)(col0 + r) * 256 + kk + q);
    }
    __syncthreads();
    #pragma unroll
    for (int ks = 0; ks < 2; ks++) {
      bf16x8 af[4], bfr[4];
      #pragma unroll
      for (int i = 0; i < 4; i++) {
        af[i]  = *(const bf16x8*)(&As[(wm * 64 + i * 16 + (lane & 15)) * LDA + ks * 32 + (lane >> 4) * 8]);
        bfr[i] = *(const bf16x8*)(&Bs[(wn * 64 + i * 16 + (lane & 15)) * LDA + ks * 32 + (lane >> 4) * 8]);
      }
      #pragma unroll
      for (int i = 0; i < 4; i++)
        #pragma unroll
        for (int j = 0; j < 4; j++)
          acc[i][j] = __builtin_amdgcn_mfma_f32_16x16x32_bf16(af[i], bfr[j], acc[i][j], 0, 0, 0);
    }
    __syncthreads();
  }
  // epilogue: +bias, cvt bf16, store. C/D: col=lane&15, row=4*(lane>>4)+q (m89)
  #pragma unroll
  for (int j = 0; j < 4; j++) {
    int c = col0 + wn * 64 + j * 16 + (lane & 15);
    float bv = bias[c];
    #pragma unroll
    for (int i = 0; i < 4; i++) {
      int r0 = row0 + wm * 64 + i * 16 + (lane >> 4) * 4;
      #pragma unroll
      for (int q = 0; q < 4; q++)
        C[(size_t)(r0 + q) * 256 + c] = f2b(acc[i][j][q] + bv);
    }
  }
}

// ---------- fused: gather K, feat dot, 3-layer silu MLP, combine, f32 out ----------
// grid = B*N/2 = 4096; block = 512 = 8 waves; wave = head h; lane = (nsub, m)
__global__ __launch_bounds__(512) void fused_main(
    const u16* __restrict__ Kbf, const u16* __restrict__ Qbf,
    const int* __restrict__ nidx, const float* __restrict__ g,
    const float* __restrict__ W0t, const float* __restrict__ b0,
    const float* __restrict__ W1t, const float* __restrict__ b1,
    const float* __restrict__ W2, const float* __restrict__ b2,
    float* __restrict__ out) {
  __shared__ float lout[512];
  const int t = threadIdx.x;
  const int h = t >> 6, lane = t & 63;
  const int blk = blockIdx.x;
  const int b = blk >> 11;
  const int n0 = (blk & 2047) * 2;
  const int nsub = lane >> 5, m = lane & 31;
  const int bn = b * 4096 + n0 + nsub;
  const int row = bn * 32 + m;                 // flat (b,n,m)
  const int kidx = nidx[row];
  const size_t krow = (size_t)b * 4096 + (size_t)kidx;

  // feat = (Q[bn,h,:] . K[b,idx,h,:]) / sqrt(32), bf16 staged K/Q
  const uint4* qp = (const uint4*)(Qbf + (size_t)bn * 256 + h * 32);
  const uint4* kp = (const uint4*)(Kbf + krow * 256 + h * 32);
  float dot = 0.f;
  #pragma unroll
  for (int s = 0; s < 4; s++) {
    uint4 qv = qp[s], kv = kp[s];
    dot += b2f_lo(qv.x) * b2f_lo(kv.x) + b2f_hi(qv.x) * b2f_hi(kv.x);
    dot += b2f_lo(qv.y) * b2f_lo(kv.y) + b2f_hi(qv.y) * b2f_hi(kv.y);
    dot += b2f_lo(qv.z) * b2f_lo(kv.z) + b2f_hi(qv.z) * b2f_hi(kv.z);
    dot += b2f_lo(qv.w) * b2f_lo(kv.w) + b2f_hi(qv.w) * b2f_hi(kv.w);
  }
  const float feat = dot * 0.17677669529663687f;

  // MLP with wave-uniform (scalarized) f32 weight tables
  const int hs = __builtin_amdgcn_readfirstlane(h);
  const float* __restrict__ w0  = W0t + hs * 160;   // [jout][l]
  const float* __restrict__ w1  = W1t + hs * 256;   // [jout][jin]
  const float* __restrict__ w2  = W2 + hs * 16;
  const float* __restrict__ bb0 = b0 + hs * 16;
  const float* __restrict__ bb1 = b1 + hs * 16;

  float gv[10];
  const float* gp = g + (size_t)row * 10;           // 40B stride, 8B aligned
  #pragma unroll
  for (int i = 0; i < 5; i++) {
    float2 v = *(const float2*)(gp + 2 * i);
    gv[2 * i] = v.x; gv[2 * i + 1] = v.y;
  }
  float h0[16];
  #pragma unroll
  for (int j = 0; j < 16; j++) {
    float a = bb0[j];
    #pragma unroll
    for (int l = 0; l < 10; l++) a += gv[l] * w0[j * 10 + l];
    h0[j] = silu_f(a);
  }
  float loc = 0.f;
  #pragma unroll
  for (int k = 0; k < 16; k++) {
    float a = bb1[k];
    #pragma unroll
    for (int j = 0; j < 16; j++) a += h0[j] * w1[k * 16 + j];
    loc += silu_f(a) * w2[k];
  }
  loc = silu_f(loc + b2[hs]);

  // combine + coalesced f32 store via LDS bounce: out idx = blk*512 + lane*8 + h
  lout[lane * 8 + h] = feat + loc;
  __syncthreads();
  if (t < 128) {
    float4 v = ((const float4*)lout)[t];
    ((float4*)out)[(size_t)blk * 128 + t] = v;
  }
}

extern "C" void kernel_launch(void* const* d_in, const int* in_sizes, int n_in,
                              void* d_out, int out_size, void* d_ws, size_t ws_size,
                              hipStream_t stream) {
  const float* g_in = (const float*)d_in[0];
  // d_in[1] = nbhd_mask: unused by the reference
  const float* kf   = (const float*)d_in[2];
  const float* qf   = (const float*)d_in[3];
  const int*   idx  = (const int*)d_in[4];
  const float* Wk   = (const float*)d_in[5];
  const float* bk   = (const float*)d_in[6];
  const float* Wq   = (const float*)d_in[7];
  const float* bq   = (const float*)d_in[8];
  const float* W0   = (const float*)d_in[9];
  const float* b0   = (const float*)d_in[10];
  const float* W1   = (const float*)d_in[11];
  const float* b1   = (const float*)d_in[12];
  const float* W2   = (const float*)d_in[13];
  const float* b2   = (const float*)d_in[14];

  char* ws = (char*)d_ws;
  u16*   Kbf = (u16*)ws;                                      // 4 MB
  u16*   Qbf = (u16*)(ws + 4u * 1024 * 1024);                 // 4 MB
  u16*   Wkt = (u16*)(ws + 8u * 1024 * 1024);                 // 128 KB
  u16*   Wqt = (u16*)(ws + 8u * 1024 * 1024 + 131072);        // 128 KB
  float* W0t = (float*)(ws + 8u * 1024 * 1024 + 262144);      // 5120 B
  float* W1t = (float*)(ws + 8u * 1024 * 1024 + 262144 + 5120); // 8192 B

  prep_wt<<<64, 256, 0, stream>>>(Wk, Wq, Wkt, Wqt);
  prep_mlpw<<<1, 256, 0, stream>>>(W0, W1, W0t, W1t);
  gemm_proj<<<dim3(64, 2, 2), 256, 0, stream>>>(kf, qf, Wkt, Wqt, bk, bq, Kbf, Qbf);
  fused_main<<<4096, 512, 0, stream>>>(Kbf, Qbf, idx, g_in, W0t, b0, W1t, b1, W2, b2,
                                       (float*)d_out);
}

// Round 4
// 76.490 us; speedup vs baseline: 1.1436x; 1.1436x over previous
//
#include <hip/hip_runtime.h>

typedef unsigned int   u32;
typedef unsigned short u16;
typedef __bf16 bf16x8 __attribute__((ext_vector_type(8)));
typedef float  f32x4  __attribute__((ext_vector_type(4)));
typedef float  f32x16 __attribute__((ext_vector_type(16)));

__device__ __forceinline__ u16 f2b(float f) {
  u32 u = __float_as_uint(f);
  u = (u + 0x7fffu + ((u >> 16) & 1u)) >> 16;   // RNE
  return (u16)u;
}
__device__ __forceinline__ float b2f_lo(u32 u) { return __uint_as_float(u << 16); }
__device__ __forceinline__ float b2f_hi(u32 u) { return __uint_as_float(u & 0xffff0000u); }
__device__ __forceinline__ float silu_f(float x) { return __fdividef(x, 1.f + __expf(-x)); }

// ---------- prep: Wk/Wq (256x256 f32, [k][n]) -> bf16 [n][k] ----------
__global__ void prep_wt(const float* __restrict__ Wk, const float* __restrict__ Wq,
                        u16* __restrict__ Wkt, u16* __restrict__ Wqt) {
  for (int idx = blockIdx.x * 256 + threadIdx.x; idx < 256 * 256; idx += gridDim.x * 256) {
    int n = idx >> 8, k = idx & 255;
    Wkt[idx] = f2b(Wk[k * 256 + n]);
    Wqt[idx] = f2b(Wq[k * 256 + n]);
  }
}

// ---------- prep: build per-head MFMA A-fragment tables for the MLP ----------
// 32x32x16 A-frag: lane l -> row = l&31, k-slot = 8*(l>>5)+e (e=0..7)
// W0A: A = W0^T  (row=j_out<16, k=l_dim<10, else 0)
// W1A: A = W1^T with k-slots permuted by sigma(s)=(s&3)+8*((s>>2)&1)+4*(s>>3)
//      so that layer-0's C-layout output packs directly into layer-1's B-frag.
__global__ void prep_mlpfrag(const float* __restrict__ W0, const float* __restrict__ W1,
                             u16* __restrict__ W0A, u16* __restrict__ W1A) {
  int t = threadIdx.x;            // 512 = 8 heads x 64 lanes
  int h = t >> 6, l = t & 63;
  int hf = l >> 5, j = l & 31;    // j = A-row (output index)
  #pragma unroll
  for (int e = 0; e < 8; e++) {
    int k = 8 * hf + e;           // k-slot
    float v0 = (j < 16 && k < 10) ? W0[h * 160 + k * 16 + j] : 0.f;
    W0A[t * 8 + e] = f2b(v0);
    int jin = (k & 3) + 8 * ((k >> 2) & 1) + 4 * (k >> 3);  // sigma(k)
    float v1 = (j < 16) ? W1[h * 256 + jin * 16 + j] : 0.f;
    W1A[t * 8 + e] = f2b(v1);
  }
}

// ---------- GEMM: C_bf16[8192][256] = A_f32[8192][256] @ W + bias ----------
#define LDA 72
__global__ __launch_bounds__(256) void gemm_proj(
    const float* __restrict__ A0, const float* __restrict__ A1,
    const u16* __restrict__ B0, const u16* __restrict__ B1,
    const float* __restrict__ bias0, const float* __restrict__ bias1,
    u16* __restrict__ C0, u16* __restrict__ C1) {
  const float* A; const u16* Bt; const float* bias; u16* C;
  if (blockIdx.z == 0) { A = A0; Bt = B0; bias = bias0; C = C0; }
  else                 { A = A1; Bt = B1; bias = bias1; C = C1; }
  __shared__ __align__(16) u16 As[128 * LDA];
  __shared__ __align__(16) u16 Bs[128 * LDA];
  const int t = threadIdx.x;
  const int w = t >> 6, lane = t & 63;
  const int wm = w >> 1, wn = w & 1;
  const int row0 = blockIdx.x * 128, col0 = blockIdx.y * 128;
  f32x4 acc[4][4] = {};
  for (int kk = 0; kk < 256; kk += 64) {
    #pragma unroll
    for (int p = 0; p < 8; p++) {
      int r = p * 16 + (t >> 4), q = (t & 15) * 4;
      float4 v = *(const float4*)(A + (size_t)(row0 + r) * 256 + kk + q);
      uint2 pk;
      pk.x = (u32)f2b(v.x) | ((u32)f2b(v.y) << 16);
      pk.y = (u32)f2b(v.z) | ((u32)f2b(v.w) << 16);
      *(uint2*)(&As[r * LDA + q]) = pk;
    }
    #pragma unroll
    for (int p = 0; p < 4; p++) {
      int r = p * 32 + (t >> 3), q = (t & 7) * 8;
      *(uint4*)(&Bs[r * LDA + q]) = *(const uint4*)(Bt + (size_t)(col0 + r) * 256 + kk + q);
    }
    __syncthreads();
    #pragma unroll
    for (int ks = 0; ks < 2; ks++) {
      bf16x8 af[4], bfr[4];
      #pragma unroll
      for (int i = 0; i < 4; i++) {
        af[i]  = *(const bf16x8*)(&As[(wm * 64 + i * 16 + (lane & 15)) * LDA + ks * 32 + (lane >> 4) * 8]);
        bfr[i] = *(const bf16x8*)(&Bs[(wn * 64 + i * 16 + (lane & 15)) * LDA + ks * 32 + (lane >> 4) * 8]);
      }
      #pragma unroll
      for (int i = 0; i < 4; i++)
        #pragma unroll
        for (int j = 0; j < 4; j++)
          acc[i][j] = __builtin_amdgcn_mfma_f32_16x16x32_bf16(af[i], bfr[j], acc[i][j], 0, 0, 0);
    }
    __syncthreads();
  }
  #pragma unroll
  for (int j = 0; j < 4; j++) {
    int c = col0 + wn * 64 + j * 16 + (lane & 15);
    float bv = bias[c];
    #pragma unroll
    for (int i = 0; i < 4; i++) {
      int r0 = row0 + wm * 64 + i * 16 + (lane >> 4) * 4;
      #pragma unroll
      for (int q = 0; q < 4; q++)
        C[(size_t)(r0 + q) * 256 + c] = f2b(acc[i][j][q] + bv);
    }
  }
}

// ---------- fused v2: gather+dot (VALU) + MLP (MFMA, swapped operands) ----------
// grid = B*N = 8192 blocks; block = 512 = 8 waves; wave = head; lane = (hf, m)
__global__ __launch_bounds__(512) void fused_main(
    const u16* __restrict__ Kbf, const u16* __restrict__ Qbf,
    const int* __restrict__ nidx, const float* __restrict__ g,
    const u16* __restrict__ W0A, const u16* __restrict__ W1A,
    const float* __restrict__ b0, const float* __restrict__ b1,
    const float* __restrict__ W2, const float* __restrict__ b2,
    float* __restrict__ out) {
  __shared__ float lout[256];
  const int t = threadIdx.x;
  const int h = t >> 6, lane = t & 63;
  const int hf = lane >> 5, m = lane & 31;
  const int bn = blockIdx.x;                   // flat (b,n)
  const int b = bn >> 12;
  const int row = bn * 32 + m;                 // flat (b,n,m)
  const int hs = __builtin_amdgcn_readfirstlane(h);

  // ---- MFMA A-fragments (per-head weight tables) ----
  const bf16x8 a0 = *(const bf16x8*)(W0A + (size_t)(hs * 64 + lane) * 8);
  const bf16x8 a1 = *(const bf16x8*)(W1A + (size_t)(hs * 64 + lane) * 8);

  // ---- g B-fragment: col = m (row of MLP), k-slot = 8*hf+e -> g[row][k] (k<10) ----
  const float* gp = g + (size_t)row * 10;
  float2 v0 = *(const float2*)(gp + hf * 8);   // hf=0: g0,g1 ; hf=1: g8,g9
  float2 v1, v2, v3;
  if (hf == 0) {
    v1 = *(const float2*)(gp + 2); v2 = *(const float2*)(gp + 4); v3 = *(const float2*)(gp + 6);
  } else {
    v1 = make_float2(0.f, 0.f); v2 = v1; v3 = v1;
  }
  bf16x8 gb;
  gb[0] = (__bf16)v0.x; gb[1] = (__bf16)v0.y;
  gb[2] = (__bf16)v1.x; gb[3] = (__bf16)v1.y;
  gb[4] = (__bf16)v2.x; gb[5] = (__bf16)v2.y;
  gb[6] = (__bf16)v3.x; gb[7] = (__bf16)v3.y;

  // ---- feat dot (split across lane halves, d = hf*16 .. hf*16+15) ----
  const int kidx = nidx[row];
  const size_t krow = (size_t)b * 4096 + (size_t)kidx;
  const uint4* qp = (const uint4*)(Qbf + (size_t)bn * 256 + h * 32 + hf * 16);
  const uint4* kp = (const uint4*)(Kbf + krow * 256 + h * 32 + hf * 16);
  uint4 q0 = qp[0], q1 = qp[1], k0 = kp[0], k1 = kp[1];
  float dpart = 0.f;
  dpart += b2f_lo(q0.x) * b2f_lo(k0.x) + b2f_hi(q0.x) * b2f_hi(k0.x);
  dpart += b2f_lo(q0.y) * b2f_lo(k0.y) + b2f_hi(q0.y) * b2f_hi(k0.y);
  dpart += b2f_lo(q0.z) * b2f_lo(k0.z) + b2f_hi(q0.z) * b2f_hi(k0.z);
  dpart += b2f_lo(q0.w) * b2f_lo(k0.w) + b2f_hi(q0.w) * b2f_hi(k0.w);
  dpart += b2f_lo(q1.x) * b2f_lo(k1.x) + b2f_hi(q1.x) * b2f_hi(k1.x);
  dpart += b2f_lo(q1.y) * b2f_lo(k1.y) + b2f_hi(q1.y) * b2f_hi(k1.y);
  dpart += b2f_lo(q1.z) * b2f_lo(k1.z) + b2f_hi(q1.z) * b2f_hi(k1.z);
  dpart += b2f_lo(q1.w) * b2f_lo(k1.w) + b2f_hi(q1.w) * b2f_hi(k1.w);

  // ---- layer 0: D0 = W0^T . g^T  -> lane holds h0[j] for its row, j=c_e+4*hf ----
  const float* __restrict__ bb0 = b0 + hs * 16;
  const float* __restrict__ bb1 = b1 + hs * 16;
  const float* __restrict__ w2  = W2 + hs * 16;
  f32x16 zero = {};
  f32x16 acc0 = __builtin_amdgcn_mfma_f32_32x32x16_bf16(a0, gb, zero, 0, 0, 0);
  bf16x8 h0b;
  #pragma unroll
  for (int e = 0; e < 8; e++) {
    int c = (e & 3) + 8 * (e >> 2);          // compile-time
    float bj = hf ? bb0[c + 4] : bb0[c];     // scalar loads + cndmask
    h0b[e] = (__bf16)silu_f(acc0[e] + bj);
  }
  // ---- layer 1: D1 = (W1^T, sigma-permuted) . h0^T ----
  f32x16 acc1 = __builtin_amdgcn_mfma_f32_32x32x16_bf16(a1, h0b, zero, 0, 0, 0);
  float part = 0.f;
  #pragma unroll
  for (int e = 0; e < 8; e++) {
    int c = (e & 3) + 8 * (e >> 2);
    float bj = hf ? bb1[c + 4] : bb1[c];
    float wj = hf ? w2[c + 4] : w2[c];
    part += silu_f(acc1[e] + bj) * wj;
  }

  // ---- cross-half combine + final ----
  float osum = part + __shfl_xor(part, 32, 64);
  float feat = (dpart + __shfl_xor(dpart, 32, 64)) * 0.17677669529663687f;
  float res = feat + silu_f(osum + b2[hs]);

  if (hf == 0) lout[m * 8 + h] = res;        // out idx within block = m*8+h
  __syncthreads();
  if (t < 64) {
    float4 v = ((const float4*)lout)[t];
    ((float4*)(out + (size_t)bn * 256))[t] = v;
  }
}

extern "C" void kernel_launch(void* const* d_in, const int* in_sizes, int n_in,
                              void* d_out, int out_size, void* d_ws, size_t ws_size,
                              hipStream_t stream) {
  const float* g_in = (const float*)d_in[0];
  // d_in[1] = nbhd_mask: unused by the reference
  const float* kf   = (const float*)d_in[2];
  const float* qf   = (const float*)d_in[3];
  const int*   idx  = (const int*)d_in[4];
  const float* Wk   = (const float*)d_in[5];
  const float* bk   = (const float*)d_in[6];
  const float* Wq   = (const float*)d_in[7];
  const float* bq   = (const float*)d_in[8];
  const float* W0   = (const float*)d_in[9];
  const float* b0   = (const float*)d_in[10];
  const float* W1   = (const float*)d_in[11];
  const float* b1   = (const float*)d_in[12];
  const float* W2   = (const float*)d_in[13];
  const float* b2   = (const float*)d_in[14];

  char* ws = (char*)d_ws;
  u16* Kbf = (u16*)ws;                                       // 4 MB
  u16* Qbf = (u16*)(ws + 4u * 1024 * 1024);                  // 4 MB
  u16* Wkt = (u16*)(ws + 8u * 1024 * 1024);                  // 128 KB
  u16* Wqt = (u16*)(ws + 8u * 1024 * 1024 + 131072);         // 128 KB
  u16* W0A = (u16*)(ws + 8u * 1024 * 1024 + 262144);         // 8 KB
  u16* W1A = (u16*)(ws + 8u * 1024 * 1024 + 262144 + 8192);  // 8 KB

  prep_wt<<<64, 256, 0, stream>>>(Wk, Wq, Wkt, Wqt);
  prep_mlpfrag<<<1, 512, 0, stream>>>(W0, W1, W0A, W1A);
  gemm_proj<<<dim3(64, 2, 2), 256, 0, stream>>>(kf, qf, Wkt, Wqt, bk, bq, Kbf, Qbf);
  fused_main<<<8192, 512, 0, stream>>>(Kbf, Qbf, idx, g_in, W0A, W1A, b0, b1, W2, b2,
                                       (float*)d_out);
}